// Round 1
// baseline (237.201 us; speedup 1.0000x reference)
//
#include <hip/hip_runtime.h>

// Seesaw_Conv: 3x3 conv (16->128) offsets -> scrambled bilinear sampling -> 9-tap weighted sum + residual
// Shapes: B=4, C=16, H=W=192, K=3, KE=9, M=4
// ws layout: [0,73728): W transposed [144][128]; [73728, +75497472): off buffer NHWC (B,H,W,128)

#define HH 192
#define WW 192
#define CC 16
#define CO 128
#define KE 9

__global__ __launch_bounds__(256) void transpose_w_kernel(
    const float* __restrict__ Wref, float* __restrict__ Wt) {
  int i = blockIdx.x * 256 + threadIdx.x;
  if (i < CO * 144) {
    int o = i / 144, term = i - o * 144;
    Wt[term * CO + o] = Wref[i];
  }
}

// Direct conv: out[b,o,h,w] = sum_{cin,kh,kw} x[b,cin,h+kh-1,w+kw-1] * W[o,cin,kh,kw] + bref[o]
// Block: one (b,h), 64 w, 64 couts. Thread: 2 w x 8 couts.
__global__ __launch_bounds__(256) void conv_kernel(
    const float* __restrict__ x, const float* __restrict__ Wt,
    const float* __restrict__ bref, float* __restrict__ off) {
  __shared__ float sW[144][64];     // [term][cout_local]  36.9 KB
  __shared__ float sX[16][3][66];   // [cin][kh][w+halo]   12.7 KB
  int bid = blockIdx.x;
  int ct = bid & 1;
  int wt = (bid >> 1) % 3;
  int h  = (bid / 6) % HH;
  int b  = bid / (6 * HH);
  int co0 = ct * 64;
  int w0 = wt * 64;
  int t = threadIdx.x;
  // stage weights: global coalesced (term-major, cout fast), LDS write conflict-free
  for (int i = t; i < 144 * 64; i += 256) {
    int term = i >> 6, cl = i & 63;
    sW[term][cl] = Wt[term * CO + co0 + cl];
  }
  // stage x tile rows h-1..h+1, w0-1..w0+64 with zero padding
  for (int i = t; i < 16 * 3 * 66; i += 256) {
    int cin = i / 198;
    int r = i - cin * 198;
    int kh = r / 66;
    int wl = r - kh * 66;
    int gh = h + kh - 1;
    int gw = w0 + wl - 1;
    float v = 0.0f;
    if (gh >= 0 && gh < HH && gw >= 0 && gw < WW)
      v = x[((b * CC + cin) * HH + gh) * WW + gw];
    sX[cin][kh][wl] = v;
  }
  __syncthreads();
  int wg = t & 31;   // 32 w-groups of 2
  int cg = t >> 5;   // 8 cout-groups of 8
  int wl = wg * 2;
  float acc[2][8];
  #pragma unroll
  for (int j = 0; j < 2; ++j)
    #pragma unroll
    for (int k = 0; k < 8; ++k) acc[j][k] = 0.0f;
  for (int cin = 0; cin < 16; ++cin) {
    #pragma unroll
    for (int kh = 0; kh < 3; ++kh) {
      float2 xa = *(const float2*)&sX[cin][kh][wl];
      float2 xb = *(const float2*)&sX[cin][kh][wl + 2];
      float xw[4] = {xa.x, xa.y, xb.x, xb.y};
      int term0 = (cin * 3 + kh) * 3;
      #pragma unroll
      for (int kw = 0; kw < 3; ++kw) {
        float4 wa = *(const float4*)&sW[term0 + kw][cg * 8];
        float4 wb = *(const float4*)&sW[term0 + kw][cg * 8 + 4];
        #pragma unroll
        for (int j = 0; j < 2; ++j) {
          float xv = xw[kw + j];
          acc[j][0] += xv * wa.x;  acc[j][1] += xv * wa.y;
          acc[j][2] += xv * wa.z;  acc[j][3] += xv * wa.w;
          acc[j][4] += xv * wb.x;  acc[j][5] += xv * wb.y;
          acc[j][6] += xv * wb.z;  acc[j][7] += xv * wb.w;
        }
      }
    }
  }
  float4 ba = *(const float4*)&bref[co0 + cg * 8];
  float4 bb = *(const float4*)&bref[co0 + cg * 8 + 4];
  #pragma unroll
  for (int j = 0; j < 2; ++j) {
    int w = w0 + wl + j;
    size_t pos = ((size_t)((b * HH + h) * WW + w)) * CO + co0 + cg * 8;
    float4 o0 = {acc[j][0] + ba.x, acc[j][1] + ba.y, acc[j][2] + ba.z, acc[j][3] + ba.w};
    float4 o1 = {acc[j][4] + bb.x, acc[j][5] + bb.y, acc[j][6] + bb.z, acc[j][7] + bb.w};
    *(float4*)&off[pos] = o0;
    *(float4*)&off[pos + 4] = o1;
  }
}

// Fused: for each output (b,c,h,w) [NCHW], decompose its 9 scrambled flat indices,
// bilinear-sample x, apply W_ws, add b_ws + residual x.
__global__ __launch_bounds__(256) void sample_kernel(
    const float* __restrict__ x, const float* __restrict__ off,
    const float* __restrict__ Wws, const float* __restrict__ bws,
    float* __restrict__ out) {
  int tid = blockIdx.x * 256 + threadIdx.x;
  if (tid >= 4 * CC * HH * WW) return;
  int w = tid % WW;
  int t1 = tid / WW;
  int h = t1 % HH;
  int t2 = t1 / HH;
  int c = t2 & 15;
  int b = t2 >> 4;
  unsigned n0 = (unsigned)((((b * HH + h) * WW + w) * CC + c) * KE);
  float acc = 0.0f;
  #pragma unroll
  for (int ke = 0; ke < KE; ++ke) {
    unsigned n = n0 + (unsigned)ke;
    // samp_t flat layout: [c2][ke2][b2][h2][w2]
    unsigned w2 = n % 192u;
    unsigned q1 = n / 192u;
    unsigned h2 = q1 % 192u;
    unsigned q2 = q1 / 192u;
    unsigned b2 = q2 & 3u;
    unsigned q3 = q2 >> 2;
    unsigned ke2 = q3 % 9u;
    unsigned c2 = q3 / 9u;
    float ox = 0.0f, oy = 0.0f;
    if (ke2 != 4u) {
      unsigned m = (ke2 < 4u) ? ke2 : (ke2 - 5u);
      unsigned obase = ((b2 * 192u + h2) * 192u + w2) * 128u + c2 * 8u + m * 2u;
      float2 o2 = *(const float2*)&off[obase];
      if (ke2 > 4u) { ox = 2.0f - o2.x; oy = 2.0f - o2.y; }
      else          { ox = o2.x;        oy = o2.y; }
    }
    // base grid: component 0 = h-linspace (used as x/width!), component 1 = w-linspace
    float xn = ox + (float)h2 * (1.0f / 191.0f);
    float yn = oy + (float)w2 * (1.0f / 191.0f);
    float ix = ((xn + 1.0f) * 192.0f - 1.0f) * 0.5f;
    float iy = ((yn + 1.0f) * 192.0f - 1.0f) * 0.5f;
    float x0f = floorf(ix), y0f = floorf(iy);
    float wx = ix - x0f, wy = iy - y0f;
    int x0 = (int)x0f, y0 = (int)y0f;
    int x1 = x0 + 1, y1 = y0 + 1;
    const float* xp = x + ((size_t)(b2 * CC + c2) * HH) * WW;
    bool xin0 = (unsigned)x0 < 192u;
    bool xin1 = (unsigned)x1 < 192u;
    bool yin0 = (unsigned)y0 < 192u;
    bool yin1 = (unsigned)y1 < 192u;
    int xc0 = min(max(x0, 0), 191), xc1 = min(max(x1, 0), 191);
    int yc0 = min(max(y0, 0), 191), yc1 = min(max(y1, 0), 191);
    float v00 = (yin0 && xin0) ? xp[yc0 * 192 + xc0] : 0.0f;
    float v01 = (yin0 && xin1) ? xp[yc0 * 192 + xc1] : 0.0f;
    float v10 = (yin1 && xin0) ? xp[yc1 * 192 + xc0] : 0.0f;
    float v11 = (yin1 && xin1) ? xp[yc1 * 192 + xc1] : 0.0f;
    float s = v00 * (1.0f - wy) * (1.0f - wx) + v01 * (1.0f - wy) * wx
            + v10 * wy * (1.0f - wx) + v11 * wy * wx;
    acc += Wws[c * KE + ke] * s;
  }
  out[tid] = acc + bws[c] + x[tid];
}

extern "C" void kernel_launch(void* const* d_in, const int* in_sizes, int n_in,
                              void* d_out, int out_size, void* d_ws, size_t ws_size,
                              hipStream_t stream) {
  (void)in_sizes; (void)n_in; (void)out_size; (void)ws_size;
  const float* x    = (const float*)d_in[0];
  const float* Wref = (const float*)d_in[1];
  const float* bref = (const float*)d_in[2];
  const float* Wws  = (const float*)d_in[3];
  const float* bws  = (const float*)d_in[4];
  float* out = (float*)d_out;
  float* Wt  = (float*)d_ws;                        // 144*128*4 = 73728 B
  float* off = (float*)((char*)d_ws + 73728);       // 4*192*192*128*4 = 75497472 B

  transpose_w_kernel<<<72, 256, 0, stream>>>(Wref, Wt);
  conv_kernel<<<4 * HH * 3 * 2, 256, 0, stream>>>(x, Wt, bref, off);
  sample_kernel<<<(4 * CC * HH * WW) / 256, 256, 0, stream>>>(x, off, Wws, bws, out);
}

// Round 2
// 192.389 us; speedup vs baseline: 1.2329x; 1.2329x over previous
//
#include <hip/hip_runtime.h>

// Seesaw_Conv: 3x3 conv (16->128) offsets -> scrambled bilinear sampling -> 9-tap weighted sum + residual
// B=4, C=16, H=W=192, KE=9, M=4
// ws layout: [0,73728): Wt[144][128]; [73728,+75497472): off pairs float2[64][4][192][192]
//   pair p = c2*4+m holds (off_x, off_y) for channel c2, offset m.

#define HH 192
#define WW 192
#define CC 16
#define CO 128

__global__ __launch_bounds__(256) void transpose_w_kernel(
    const float* __restrict__ Wref, float* __restrict__ Wt) {
  int i = blockIdx.x * 256 + threadIdx.x;
  if (i < CO * 144) {
    int o = i / 144, term = i - o * 144;
    Wt[term * CO + o] = Wref[i];
  }
}

// Direct conv, block = 2h x 64w x 64co, thread = 4w x 8co.
__global__ __launch_bounds__(256) void conv_kernel(
    const float* __restrict__ x, const float* __restrict__ Wt,
    const float* __restrict__ bref, float2* __restrict__ off2) {
  __shared__ float sW[144][64];    // 36.9 KB
  __shared__ float sX[16][4][66];  // 16.9 KB
  int bid = blockIdx.x;
  int ct = bid & 1;
  int wt = (bid >> 1) % 3;
  int hp = (bid / 6) % 96;
  int b  = bid / 576;
  int co0 = ct * 64, w0 = wt * 64, h0 = hp * 2;
  int t = threadIdx.x;
  for (int i = t; i < 144 * 64; i += 256) {
    int term = i >> 6, cl = i & 63;
    sW[term][cl] = Wt[term * CO + co0 + cl];
  }
  for (int i = t; i < 16 * 4 * 66; i += 256) {
    int cin = i / 264;
    int rem = i - cin * 264;
    int r = rem / 66;
    int wl2 = rem - r * 66;
    int gh = h0 + r - 1, gw = w0 + wl2 - 1;
    float v = 0.0f;
    if ((unsigned)gh < 192u && (unsigned)gw < 192u)
      v = x[((b * CC + cin) * HH + gh) * WW + gw];
    sX[cin][r][wl2] = v;
  }
  __syncthreads();
  int wg = t & 15, cg = (t >> 4) & 7, hr = t >> 7;
  int wl = wg * 4;
  float acc[4][8];
  #pragma unroll
  for (int j = 0; j < 4; ++j)
    #pragma unroll
    for (int k = 0; k < 8; ++k) acc[j][k] = 0.0f;
  for (int cin = 0; cin < 16; ++cin) {
    #pragma unroll
    for (int kh = 0; kh < 3; ++kh) {
      float4 xa = *(const float4*)&sX[cin][hr + kh][wl];
      float2 xb = *(const float2*)&sX[cin][hr + kh][wl + 4];
      float xw[6] = {xa.x, xa.y, xa.z, xa.w, xb.x, xb.y};
      int term0 = (cin * 3 + kh) * 3;
      #pragma unroll
      for (int kw = 0; kw < 3; ++kw) {
        float4 wa = *(const float4*)&sW[term0 + kw][cg * 8];
        float4 wb = *(const float4*)&sW[term0 + kw][cg * 8 + 4];
        #pragma unroll
        for (int j = 0; j < 4; ++j) {
          float xv = xw[kw + j];
          acc[j][0] += xv * wa.x;  acc[j][1] += xv * wa.y;
          acc[j][2] += xv * wa.z;  acc[j][3] += xv * wa.w;
          acc[j][4] += xv * wb.x;  acc[j][5] += xv * wb.y;
          acc[j][6] += xv * wb.z;  acc[j][7] += xv * wb.w;
        }
      }
    }
  }
  float bias[8];
  #pragma unroll
  for (int i = 0; i < 8; ++i) bias[i] = bref[co0 + cg * 8 + i];
  int h = h0 + hr;
  int p0 = (co0 >> 1) + cg * 4;
  #pragma unroll
  for (int k = 0; k < 4; ++k) {
    int p = p0 + k;
    float2* base = off2 + (((size_t)(p * 4 + b) * HH + h) * WW + w0 + wl);
    float4 v0 = {acc[0][2 * k] + bias[2 * k], acc[0][2 * k + 1] + bias[2 * k + 1],
                 acc[1][2 * k] + bias[2 * k], acc[1][2 * k + 1] + bias[2 * k + 1]};
    float4 v1 = {acc[2][2 * k] + bias[2 * k], acc[2][2 * k + 1] + bias[2 * k + 1],
                 acc[3][2 * k] + bias[2 * k], acc[3][2 * k + 1] + bias[2 * k + 1]};
    *(float4*)base = v0;
    *(float4*)(base + 2) = v1;
  }
}

// Ordering-B sampler: block = 4608 consecutive samp_t flat indices
// (uniform c2,ke2,b2; 24 w2-rows) = exactly 512 whole outputs.
__global__ __launch_bounds__(576) void sample_kernel(
    const float* __restrict__ x, const float2* __restrict__ off2,
    const float* __restrict__ Wws, const float* __restrict__ bws,
    float* __restrict__ out) {
  __shared__ float buf[4640];  // 4608 + swizzle pad (phys = s + s/144)
  int blk = blockIdx.x, tid = threadIdx.x;
  int c2 = blk / 288;
  int ke2 = (blk / 32) % 9;
  int b2 = (blk / 8) & 3;
  int h2_0 = (blk & 7) * 24;
  int w2 = tid % 192;
  int r0 = tid / 192;
  int td144 = tid % 144;
  int tq144 = tid / 144;
  float wt = Wws[td144];
  const float* xp = x + (size_t)(b2 * CC + c2) * (HH * WW);
  int m = (ke2 < 4) ? ke2 : (ke2 - 5);
  const float2* ob = off2 + (size_t)((c2 * 4 + m) * 4 + b2) * (HH * WW);
  bool hasOff = (ke2 != 4);
  bool neg = (ke2 > 4);
  float yn_base = (float)w2 * (1.0f / 191.0f);
  #pragma unroll
  for (int t8 = 0; t8 < 8; ++t8) {
    int s = t8 * 576 + tid;
    int h2 = h2_0 + 3 * t8 + r0;
    float ox = 0.0f, oy = 0.0f;
    if (hasOff) {
      float2 o = ob[h2 * WW + w2];
      if (neg) { ox = 2.0f - o.x; oy = 2.0f - o.y; }
      else     { ox = o.x;        oy = o.y; }
    }
    float xn = ox + (float)h2 * (1.0f / 191.0f);
    float yn = oy + yn_base;
    float ix = ((xn + 1.0f) * 192.0f - 1.0f) * 0.5f;
    float iy = ((yn + 1.0f) * 192.0f - 1.0f) * 0.5f;
    float x0f = floorf(ix), y0f = floorf(iy);
    float fx = ix - x0f, fy = iy - y0f;
    int x0 = (int)x0f, y0 = (int)y0f;
    int x1 = x0 + 1, y1 = y0 + 1;
    bool xi0 = (unsigned)x0 < 192u, xi1 = (unsigned)x1 < 192u;
    bool yi0 = (unsigned)y0 < 192u, yi1 = (unsigned)y1 < 192u;
    int xc0 = min(max(x0, 0), 191), xc1 = min(max(x1, 0), 191);
    int yc0 = min(max(y0, 0), 191), yc1 = min(max(y1, 0), 191);
    float v00 = (yi0 && xi0) ? xp[yc0 * 192 + xc0] : 0.0f;
    float v01 = (yi0 && xi1) ? xp[yc0 * 192 + xc1] : 0.0f;
    float v10 = (yi1 && xi0) ? xp[yc1 * 192 + xc0] : 0.0f;
    float v11 = (yi1 && xi1) ? xp[yc1 * 192 + xc1] : 0.0f;
    float sv = v00 * (1.0f - fy) * (1.0f - fx) + v01 * (1.0f - fy) * fx
             + v10 * fy * (1.0f - fx) + v11 * fy * fx;
    buf[s + t8 * 4 + tq144] = wt * sv;  // phys = s + s/144
  }
  __syncthreads();
  if (tid < 512) {
    int wi = tid & 31, c = tid >> 5;
    int o_l = wi * 16 + c;
    int pb = o_l * 9 + (o_l >> 4);  // phys base; lane stride 145 -> conflict-free
    float sum = 0.0f;
    #pragma unroll
    for (int k = 0; k < 9; ++k) sum += buf[pb + k];
    int b = blk / 1152;
    int h = (blk / 6) % 192;
    int w = 32 * (blk % 6) + wi;
    size_t oi = ((size_t)(b * CC + c) * HH + h) * WW + w;
    out[oi] = sum + bws[c] + x[oi];
  }
}

extern "C" void kernel_launch(void* const* d_in, const int* in_sizes, int n_in,
                              void* d_out, int out_size, void* d_ws, size_t ws_size,
                              hipStream_t stream) {
  (void)in_sizes; (void)n_in; (void)out_size; (void)ws_size;
  const float* x    = (const float*)d_in[0];
  const float* Wref = (const float*)d_in[1];
  const float* bref = (const float*)d_in[2];
  const float* Wws  = (const float*)d_in[3];
  const float* bws  = (const float*)d_in[4];
  float* out = (float*)d_out;
  float* Wt  = (float*)d_ws;                          // 73728 B
  float2* off2 = (float2*)((char*)d_ws + 73728);      // 75497472 B

  transpose_w_kernel<<<72, 256, 0, stream>>>(Wref, Wt);
  conv_kernel<<<2304, 256, 0, stream>>>(x, Wt, bref, off2);
  sample_kernel<<<4608, 576, 0, stream>>>(x, off2, Wws, bws, out);
}